// Round 1
// 675.482 us; speedup vs baseline: 1.0074x; 1.0074x over previous
//
#include <hip/hip_runtime.h>

#define HDIM 32   // hidden width
#define FDIM 64   // feature width

// Sum across each quad (4 lanes) using DPP quad_perm — pure VALU, no DS pipe.
// After both steps every lane in the quad holds the quad sum.
__device__ __forceinline__ float quad_sum(float x) {
    int v = __builtin_amdgcn_update_dpp(0, __float_as_int(x), 0xB1, 0xF, 0xF, true); // xor1
    x += __int_as_float(v);
    v = __builtin_amdgcn_update_dpp(0, __float_as_int(x), 0x4E, 0xF, 0xF, true);     // xor2
    x += __int_as_float(v);
    return x;
}

__device__ __forceinline__ float dot4(float4 a, float4 b) {
    return fmaf(a.x, b.x, fmaf(a.y, b.y, fmaf(a.z, b.z, a.w * b.w)));
}

// Per-row likelihood in closed form (theta = 2):
//   u   = risk + shape*log(t) - shape*log(scale)
//   e   = exp(u)            (log S = -e)
//   ld  = u - log t + log(shape) - e
//   A   = exp(2 e_t) + exp(2 e_c) - 1
//   logL = c*(ld_t + 3 e_t) + (1-c)*(ld_c + 3 e_c) - 1.5 log A
__device__ __forceinline__ float row_logl(float rt, float rc, float tv, float cv,
                                          float shape_t, float kt, float lsh_t,
                                          float shape_c, float kc, float lsh_c) {
    float lt  = __logf(tv);
    float u_t = fmaf(shape_t, lt, rt) - kt;
    float u_c = fmaf(shape_c, lt, rc) - kc;
    float e_t = __expf(u_t);
    float e_c = __expf(u_c);
    float ld_t = u_t - lt + lsh_t - e_t;
    float ld_c = u_c - lt + lsh_c - e_c;
    float A    = __expf(2.f * e_t) + __expf(2.f * e_c) - 1.f;
    float logA = __logf(A);
    return cv * (ld_t + 3.f * e_t) + (1.f - cv) * (ld_c + 3.f * e_c) - 1.5f * logA;
}

// 4 lanes per row (quad). Each lane now handles FOUR rows (R, R+16, R+32,
// R+48) per iteration -> 16 float4 loads in flight per thread, block tile =
// 256 rows. After the quad sums, lane c4 takes the row matching its own
// index, so the transcendental epilogue runs with ALL 64 lanes active in a
// single convergent block (was: two half-masked exec blocks).
// n % 256 == 128 for this problem, so a guarded tail path handles the rest.
__launch_bounds__(256)
__global__ void survival_kernel(const float4* __restrict__ x4,
                                const float* __restrict__ t,
                                const float* __restrict__ cv,
                                const float* __restrict__ Wt1, const float* __restrict__ bt1,
                                const float* __restrict__ Wt2, const float* __restrict__ bt2,
                                const float* __restrict__ Wc1, const float* __restrict__ bc1,
                                const float* __restrict__ Wc2, const float* __restrict__ bc2,
                                const float* __restrict__ sh_t, const float* __restrict__ sc_t,
                                const float* __restrict__ sh_c, const float* __restrict__ sc_c,
                                float* __restrict__ out, int n) {
    // ---- cooperative weight collapse: w_eff = W1 @ W2, b_eff = b1 @ W2 + b2 ----
    __shared__ __align__(16) float ws[132];   // [0..63] w_t, [64..127] w_c, [128]=b_t, [129]=b_c
    __shared__ float wsum[4];
    const int tid = threadIdx.x;
    if (tid < 128) {
        const float* W1 = (tid < 64) ? (Wt1 + tid * HDIM) : (Wc1 + (tid - 64) * HDIM);
        const float* W2 = (tid < 64) ? Wt2 : Wc2;
        float s = 0.f;
        #pragma unroll
        for (int h = 0; h < HDIM; ++h) s = fmaf(W1[h], W2[h], s);
        ws[tid] = s;
    } else if (tid < 130) {
        const float* b1 = (tid == 128) ? bt1 : bc1;
        const float* W2 = (tid == 128) ? Wt2 : Wc2;
        float b = (tid == 128) ? bt2[0] : bc2[0];
        #pragma unroll
        for (int h = 0; h < HDIM; ++h) b = fmaf(b1[h], W2[h], b);
        ws[tid] = b;
    }
    __syncthreads();

    const int lane   = tid & 63;
    const int c4     = lane & 3;        // float4-column group within row
    const int g      = lane >> 2;       // row within wave sub-tile (0..15)
    const int waveId = tid >> 6;

    // per-thread weight fragments: columns {c4, c4+4, c4+8, c4+12}
    const float4* wsv = (const float4*)ws;
    const float4 wtA = wsv[c4],          wtB = wsv[c4 + 4],
                 wtC = wsv[c4 + 8],      wtD = wsv[c4 + 12];
    const float4 wcA = wsv[16 + c4],     wcB = wsv[16 + c4 + 4],
                 wcC = wsv[16 + c4 + 8], wcD = wsv[16 + c4 + 12];
    const float bt = ws[128];
    const float bc = ws[129];

    const float shape_t = sh_t[0], scale_t = sc_t[0];
    const float shape_c = sh_c[0], scale_c = sc_c[0];
    const float kt    = shape_t * __logf(scale_t);
    const float kc    = shape_c * __logf(scale_c);
    const float lsh_t = __logf(shape_t);
    const float lsh_c = __logf(shape_c);

    float acc = 0.f;

    const int nfull   = n & ~255;              // full 256-row tiles
    const int stride  = (int)gridDim.x * 256;
    const int rowOff0 = waveId * 64 + g;       // first row this lane handles
    for (int base = (int)blockIdx.x * 256; base < nfull; base += stride) {
        const int R0   = base + rowOff0;       // wave covers [base+64w, +64)
        const int Rsel = R0 + (c4 << 4);       // row this lane's epilogue owns
        // hoist the (coalesced) scalar loads so they overlap the dot chain
        const float tv  = t[Rsel];
        const float cvv = cv[Rsel];

        const float4* p0 = x4 + (size_t)R0 * 16 + c4;
        const float4* p1 = p0 + 256;           // +16 rows
        const float4* p2 = p0 + 512;           // +32 rows
        const float4* p3 = p0 + 768;           // +48 rows
        float4 a0 = p0[0], a1 = p0[4], a2 = p0[8], a3 = p0[12];
        float4 b0 = p1[0], b1 = p1[4], b2 = p1[8], b3 = p1[12];
        float4 e0 = p2[0], e1 = p2[4], e2 = p2[8], e3 = p2[12];
        float4 f0 = p3[0], f1 = p3[4], f2 = p3[8], f3 = p3[12];

        float pt0 = dot4(a0, wtA) + dot4(a1, wtB) + dot4(a2, wtC) + dot4(a3, wtD);
        float pc0 = dot4(a0, wcA) + dot4(a1, wcB) + dot4(a2, wcC) + dot4(a3, wcD);
        float pt1 = dot4(b0, wtA) + dot4(b1, wtB) + dot4(b2, wtC) + dot4(b3, wtD);
        float pc1 = dot4(b0, wcA) + dot4(b1, wcB) + dot4(b2, wcC) + dot4(b3, wcD);
        float pt2 = dot4(e0, wtA) + dot4(e1, wtB) + dot4(e2, wtC) + dot4(e3, wtD);
        float pc2 = dot4(e0, wcA) + dot4(e1, wcB) + dot4(e2, wcC) + dot4(e3, wcD);
        float pt3 = dot4(f0, wtA) + dot4(f1, wtB) + dot4(f2, wtC) + dot4(f3, wtD);
        float pc3 = dot4(f0, wcA) + dot4(f1, wcB) + dot4(f2, wcC) + dot4(f3, wcD);

        pt0 = quad_sum(pt0);  pc0 = quad_sum(pc0);
        pt1 = quad_sum(pt1);  pc1 = quad_sum(pc1);
        pt2 = quad_sum(pt2);  pc2 = quad_sum(pc2);
        pt3 = quad_sum(pt3);  pc3 = quad_sum(pc3);

        // lane c4 takes row R0 + 16*c4 — cndmask chain, no divergence
        const float pt = (c4 == 0) ? pt0 : (c4 == 1) ? pt1 : (c4 == 2) ? pt2 : pt3;
        const float pc = (c4 == 0) ? pc0 : (c4 == 1) ? pc1 : (c4 == 2) ? pc2 : pc3;

        // convergent epilogue: all 64 lanes active
        acc += row_logl(pt + bt, pc + bc, tv, cvv,
                        shape_t, kt, lsh_t, shape_c, kc, lsh_c);
    }

    // guarded tail (handles n % 256 != 0; 128 rows for this problem)
    if (nfull < n && blockIdx.x == 0) {
        for (int base = nfull; base < n; base += 64) {
            const int R = base + waveId * 16 + g;
            float4 a0 = make_float4(0.f, 0.f, 0.f, 0.f), a1 = a0, a2 = a0, a3 = a0;
            if (R < n) {
                const float4* p = x4 + (size_t)R * 16 + c4;
                a0 = p[0]; a1 = p[4]; a2 = p[8]; a3 = p[12];
            }
            float pt = dot4(a0, wtA) + dot4(a1, wtB) + dot4(a2, wtC) + dot4(a3, wtD);
            float pc = dot4(a0, wcA) + dot4(a1, wcB) + dot4(a2, wcC) + dot4(a3, wcD);
            pt = quad_sum(pt);
            pc = quad_sum(pc);
            if (c4 == 0 && R < n) {
                acc += row_logl(pt + bt, pc + bc, t[R], cv[R],
                                shape_t, kt, lsh_t, shape_c, kc, lsh_c);
            }
        }
    }

    // wave reduce (cold path)
    #pragma unroll
    for (int m = 32; m >= 1; m >>= 1) acc += __shfl_xor(acc, m);
    if (lane == 0) wsum[waveId] = acc;
    __syncthreads();
    if (tid == 0) atomicAdd(out, wsum[0] + wsum[1] + wsum[2] + wsum[3]);
}

extern "C" void kernel_launch(void* const* d_in, const int* in_sizes, int n_in,
                              void* d_out, int out_size, void* d_ws, size_t ws_size,
                              hipStream_t stream) {
    const float* x   = (const float*)d_in[0];
    const float* t   = (const float*)d_in[1];
    const float* c   = (const float*)d_in[2];
    const float* Wt1 = (const float*)d_in[3];
    const float* bt1 = (const float*)d_in[4];
    const float* Wt2 = (const float*)d_in[5];
    const float* bt2 = (const float*)d_in[6];
    const float* Wc1 = (const float*)d_in[7];
    const float* bc1 = (const float*)d_in[8];
    const float* Wc2 = (const float*)d_in[9];
    const float* bc2 = (const float*)d_in[10];
    const float* sh_t = (const float*)d_in[11];
    const float* sc_t = (const float*)d_in[12];
    const float* sh_c = (const float*)d_in[13];
    const float* sc_c = (const float*)d_in[14];

    float* out = (float*)d_out;
    const int n = in_sizes[1];  // N rows

    hipMemsetAsync(out, 0, sizeof(float), stream);

    // 256-row tiles: 7812 full tiles / 1024 blocks ≈ 7.6 iters/block.
    // At ~140 VGPRs we expect ~4 waves/SIMD -> the whole grid is resident.
    const int grid = 1024;
    survival_kernel<<<grid, 256, 0, stream>>>((const float4*)x, t, c,
                                              Wt1, bt1, Wt2, bt2,
                                              Wc1, bc1, Wc2, bc2,
                                              sh_t, sc_t, sh_c, sc_c, out, n);
}